// Round 5
// baseline (1075.465 us; speedup 1.0000x reference)
//
#include <hip/hip_runtime.h>
#include <stdint.h>

#define NB 128   // batch
#define NT 512   // time steps
#define NI 256   // input dim
#define NH 512   // hidden dim
#define NO 256   // output dim

// ---------- bf16 helpers ----------
__device__ __forceinline__ uint16_t f2bf(float x) {
  uint32_t u = __float_as_uint(x);
  return (uint16_t)((u + 0x7fffu + ((u >> 16) & 1u)) >> 16);
}
__device__ __forceinline__ uint32_t pack2bf(float a, float b) {
  return (uint32_t)f2bf(a) | ((uint32_t)f2bf(b) << 16);
}

#if __has_builtin(__builtin_amdgcn_fdot2_f32_bf16)
typedef __bf16 bf16x2_t __attribute__((ext_vector_type(2)));
#define HAVE_DOT2 1
#endif

__device__ __forceinline__ float dot2bf(uint32_t w, uint32_t h, float acc) {
#ifdef HAVE_DOT2
  return __builtin_amdgcn_fdot2_f32_bf16(__builtin_bit_cast(bf16x2_t, w),
                                         __builtin_bit_cast(bf16x2_t, h), acc, false);
#else
  float wl = __uint_as_float(w << 16), wh = __uint_as_float(w & 0xffff0000u);
  float hl = __uint_as_float(h << 16), hh = __uint_as_float(h & 0xffff0000u);
  return fmaf(wh, hh, fmaf(wl, hl, acc));
#endif
}

__device__ __forceinline__ float dot4x(uint4 w, uint4 h, float a) {
  a = dot2bf(w.x, h.x, a);
  a = dot2bf(w.y, h.y, a);
  a = dot2bf(w.z, h.z, a);
  a = dot2bf(w.w, h.w, a);
  return a;
}

__device__ __forceinline__ float fast_tanh(float x) {
  // tanh(x) = 1 - 2/(e^{2x}+1); correct limits at +/-inf, no branches
  float e = __expf(2.0f * x);
#if __has_builtin(__builtin_amdgcn_rcpf)
  return 1.0f - 2.0f * __builtin_amdgcn_rcpf(e + 1.0f);
#else
  return 1.0f - 2.0f / (e + 1.0f);
#endif
}

typedef __bf16 bf16x8 __attribute__((ext_vector_type(8)));
typedef float f32x4 __attribute__((ext_vector_type(4)));

// ---------- kernel 0: pack W_hh quads; Wih->bf16; transpose W_out; bias sum ----------
// Recur thread t (0..511): kq8 = t>>6 (k2 in [kq8*32,+32)), owns j = (t&63)*8 + jj (jj<8).
// Quad q = jj*8 + c (c=0..7): uint4 = bf16-pairs of W_hh[j][2*k2b..+8], k2b = kq8*32 + c*4.
// Stored at WQ[q*512 + t]. q<48 -> registers, 48..51 -> LDS, 52..63 -> L2 stream.
__global__ __launch_bounds__(256) void prep_kernel(const float* __restrict__ Whh,
                                                   const float* __restrict__ Wih,
                                                   const float* __restrict__ Wout,
                                                   const float* __restrict__ bih,
                                                   const float* __restrict__ bhh,
                                                   uint4* __restrict__ WQ,
                                                   float* __restrict__ WoT,
                                                   uint2* __restrict__ Wihb32,
                                                   float* __restrict__ BS) {
  int idx = blockIdx.x * 256 + threadIdx.x;
  if (idx < 32768) {                       // WQ quads
    int q = idx >> 9, t = idx & 511;
    int jj = q >> 3, c = q & 7;
    int j = (t & 63) * 8 + jj;
    int k2b = (t >> 6) * 32 + c * 4;
    const float* row = Whh + (size_t)j * NH + 2 * k2b;
    float4 f0 = *(const float4*)row;
    float4 f1 = *(const float4*)(row + 4);
    uint4 w;
    w.x = pack2bf(f0.x, f0.y);
    w.y = pack2bf(f0.z, f0.w);
    w.z = pack2bf(f1.x, f1.y);
    w.w = pack2bf(f1.z, f1.w);
    WQ[idx] = w;
  } else if (idx < 65536) {                // Wih -> bf16 (same row-major layout)
    int i = idx - 32768;
    float4 f = *(const float4*)(Wih + (size_t)i * 4);
    uint2 p;
    p.x = pack2bf(f.x, f.y);
    p.y = pack2bf(f.z, f.w);
    Wihb32[i] = p;
  } else if (idx < 98304) {                // W_out transpose (fp32)
    int i = idx - 65536;
    int o4 = (i & 63) * 4;
    int k = i >> 6;
    float4 v;
    v.x = Wout[(size_t)(o4 + 0) * NH + k];
    v.y = Wout[(size_t)(o4 + 1) * NH + k];
    v.z = Wout[(size_t)(o4 + 2) * NH + k];
    v.w = Wout[(size_t)(o4 + 3) * NH + k];
    *(float4*)&WoT[(size_t)k * NO + o4] = v;
  } else if (idx < 98816) {                // bias sum
    int n = idx - 98304;
    BS[n] = bih[n] + bhh[n];
  }
}

// ---------- kernel 1: x_proj GEMM via bf16 MFMA ----------
// XP[m][n] = sum_k inputs[m][k]*Wih[n][k] + BS[n].  D[n][m] orientation:
// lane holds 4 consecutive n at fixed m -> one dwordx2 store per tile.
__global__ __launch_bounds__(256, 2) void xproj_kernel(const float* __restrict__ A,
                                                       const uint16_t* __restrict__ Wihb,
                                                       const float* __restrict__ BS,
                                                       uint16_t* __restrict__ XP) {
  const int w = threadIdx.x >> 6;
  const int l = threadIdx.x & 63;
  const int sl = l & 15, quad = l >> 4;
  const int m = blockIdx.x * 64 + w * 16 + sl;   // input row this lane supplies

  f32x4 acc[32] = {};
  const float* arow = A + (size_t)m * NI;

  for (int k0 = 0; k0 < NI; k0 += 32) {
    float4 f0 = *(const float4*)(arow + k0 + quad * 8);
    float4 f1 = *(const float4*)(arow + k0 + quad * 8 + 4);
    uint4 ap;
    ap.x = pack2bf(f0.x, f0.y);
    ap.y = pack2bf(f0.z, f0.w);
    ap.z = pack2bf(f1.x, f1.y);
    ap.w = pack2bf(f1.z, f1.w);
    bf16x8 afrag = __builtin_bit_cast(bf16x8, ap);
#pragma unroll
    for (int u = 0; u < 32; ++u) {
      uint4 bp = *(const uint4*)(Wihb + (size_t)(u * 16 + sl) * NI + k0 + quad * 8);
      acc[u] = __builtin_amdgcn_mfma_f32_16x16x32_bf16(
          __builtin_bit_cast(bf16x8, bp), afrag, acc[u], 0, 0, 0);
    }
  }

  uint16_t* xrow = XP + (size_t)m * NH;
#pragma unroll
  for (int u = 0; u < 32; ++u) {
    float4 bs = *(const float4*)(BS + u * 16 + quad * 4);
    uint2 pw;
    pw.x = pack2bf(acc[u][0] + bs.x, acc[u][1] + bs.y);
    pw.y = pack2bf(acc[u][2] + bs.z, acc[u][3] + bs.w);
    *(uint2*)(xrow + u * 16 + quad * 4) = pw;
  }
}

// ---------- kernel 2: recurrence, W_hh split reg(48q) + LDS(4q) + L2 stream(12q) ----------
__global__ __launch_bounds__(512, 2) void recur_kernel(const uint4* __restrict__ WQ,
                                                       const float* __restrict__ WoT,
                                                       const uint16_t* __restrict__ XP,
                                                       const float* __restrict__ h0,
                                                       const float* __restrict__ bout,
                                                       float* __restrict__ out) {
  __shared__ uint4 WL[4][512];                  // 32 KB: quads q=48..51 (jj=6, c=0..3)
  __shared__ __align__(16) uint16_t h2[2][NH];  // 2 KB
  __shared__ float P[8][NH];                    // 16 KB: k-split partials
  __shared__ float hsf[NH];                     // 2 KB
  const int t = threadIdx.x;
  const int b = blockIdx.x;
  const int kq8 = t >> 6;          // k-eighth
  const int jb = (t & 63) * 8;     // first owned output
  const float invT = 1.0f / (float)NT;

  uint4 Wr[48];
#pragma unroll
  for (int q = 0; q < 48; ++q) Wr[q] = WQ[q * 512 + t];
#pragma unroll
  for (int i = 0; i < 4; ++i) WL[i][t] = WQ[(48 + i) * 512 + t];

  // L2-resident overflow streams (per-thread column, stride 512 quads per chunk)
  const uint4* gw6 = WQ + 52 * 512 + t;   // jj=6, c=4..7 at gw6[(c-4)*512]
  const uint4* gw7 = WQ + 56 * 512 + t;   // jj=7, c=0..7 at gw7[c*512]

  float hj = h0[t];
  h2[0][t] = f2bf(hj);
  __syncthreads();

  const uint16_t* xpb = XP + (size_t)b * NT * NH;

  for (int ts = 0; ts < NT; ++ts) {
    const int cur = ts & 1;
    // issue global loads first (VMEM pipe): XP, all 4 g6, first 2 g7
    float xpj = __uint_as_float((uint32_t)xpb[(size_t)ts * NH + t] << 16);
    uint4 g6_0 = gw6[0 * 512], g6_1 = gw6[1 * 512], g6_2 = gw6[2 * 512], g6_3 = gw6[3 * 512];
    uint4 g7a = gw7[0 * 512];
    uint4 g7b = gw7[1 * 512];

    const uint32_t* hw = (const uint32_t*)h2[cur] + kq8 * 32;
    float a0 = 0.f, a1 = 0.f, a2 = 0.f, a3 = 0.f;
    float a4 = 0.f, a5 = 0.f, a6 = 0.f, a7 = 0.f;

    uint4 hv0 = *(const uint4*)(hw);
    uint4 hv1 = *(const uint4*)(hw + 4);
    uint4 wl_n = WL[0][t];
#pragma unroll
    for (int c = 0; c < 8; ++c) {
      uint4 hv = hv0;
      hv0 = hv1;
      if (c < 6) hv1 = *(const uint4*)(hw + (c + 2) * 4);
      // jj=6 weight: LDS for c<4 (rolling), else pre-issued global
      uint4 w6;
      if (c < 4) {
        w6 = wl_n;
        if (c < 3) wl_n = WL[c + 1][t];
      } else {
        w6 = (c == 4) ? g6_0 : (c == 5) ? g6_1 : (c == 6) ? g6_2 : g6_3;
      }
      // jj=7 weight: rolling depth-2 L2 stream
      uint4 w7 = g7a;
      g7a = g7b;
      if (c < 6) g7b = gw7[(c + 2) * 512];

      a0 = dot4x(Wr[c], hv, a0);
      a1 = dot4x(Wr[8 + c], hv, a1);
      a2 = dot4x(Wr[16 + c], hv, a2);
      a3 = dot4x(Wr[24 + c], hv, a3);
      a4 = dot4x(Wr[32 + c], hv, a4);
      a5 = dot4x(Wr[40 + c], hv, a5);
      a6 = dot4x(w6, hv, a6);
      a7 = dot4x(w7, hv, a7);
    }
    *(float4*)&P[kq8][jb] = make_float4(a0, a1, a2, a3);
    *(float4*)&P[kq8][jb + 4] = make_float4(a4, a5, a6, a7);
    __syncthreads();   // P visible; all h2[cur] reads done

    float y = ((P[0][t] + P[1][t]) + (P[2][t] + P[3][t])) +
              ((P[4][t] + P[5][t]) + (P[6][t] + P[7][t]));
    float hnew = fmaf(fast_tanh(xpj + y), invT, hj);
    hj = hnew;
    h2[cur ^ 1][t] = f2bf(hnew);
    __syncthreads();   // new h visible
  }

  hsf[t] = hj;
  __syncthreads();

  if (t < NO) {
    float c0 = 0.f, c1 = 0.f;
#pragma unroll 4
    for (int k = 0; k < NH; k += 2) {
      c0 = fmaf(WoT[(size_t)k * NO + t], hsf[k], c0);
      c1 = fmaf(WoT[(size_t)(k + 1) * NO + t], hsf[k + 1], c1);
    }
    out[(size_t)b * NO + t] = c0 + c1 + bout[t];
  }
}

// ---------- launch ----------
extern "C" void kernel_launch(void* const* d_in, const int* in_sizes, int n_in,
                              void* d_out, int out_size, void* d_ws, size_t ws_size,
                              hipStream_t stream) {
  const float* inputs = (const float*)d_in[0];
  const float* Wih    = (const float*)d_in[1];
  const float* bih    = (const float*)d_in[2];
  const float* Whh    = (const float*)d_in[3];
  const float* bhh    = (const float*)d_in[4];
  const float* Wout   = (const float*)d_in[5];
  const float* bout   = (const float*)d_in[6];
  const float* h0     = (const float*)d_in[7];
  float* out = (float*)d_out;

  char* ws = (char*)d_ws;
  uint4*    WQ     = (uint4*)ws;                          // 512 KB
  float*    WoT    = (float*)(ws + (512u << 10));         // 512 KB
  uint2*    Wihb32 = (uint2*)(ws + (1024u << 10));        // 256 KB
  float*    BS     = (float*)(ws + (1280u << 10));        // 2 KB
  uint16_t* XP     = (uint16_t*)(ws + (1536u << 10));     // 64 MB

  hipLaunchKernelGGL(prep_kernel, dim3(386), dim3(256), 0, stream,
                     Whh, Wih, Wout, bih, bhh, WQ, WoT, Wihb32, BS);
  hipLaunchKernelGGL(xproj_kernel, dim3(NB * NT / 64), dim3(256), 0, stream,
                     inputs, (const uint16_t*)Wihb32, BS, XP);
  hipLaunchKernelGGL(recur_kernel, dim3(NB), dim3(512), 0, stream,
                     WQ, WoT, XP, h0, bout, out);
}